// Round 1
// baseline (231.607 us; speedup 1.0000x reference)
//
#include <hip/hip_runtime.h>
#include <math.h>

namespace {

constexpr int B = 4;
constexpr int C = 512;
constexpr int NH = 32;          // heads
constexpr int CPH = 16;         // channels per head
constexpr int N = 32 * 32 * 32; // 32768 spatial
constexpr long BHN = (long)B * NH * N;   // 4,194,304
constexpr long YSIZE = (long)B * C * N;  // 67,108,864

__device__ inline float waveReduceSum(float v) {
#pragma unroll
  for (int o = 32; o > 0; o >>= 1) v += __shfl_xor(v, o);
  return v;
}

// ---------------------------------------------------------------------------
// k1: raw K/Q logits per (b,h,n) + per-(b,c) channel sums.
// grid (N/1024, NH, B), block 256. Each thread: float4 per channel.
// Softmax is shift-invariant so bias and -mu*w terms are dropped (they cancel).
__global__ void k1_logits_sum(const float* __restrict__ x,
                              const float* __restrict__ kw,
                              const float* __restrict__ qw,
                              float* __restrict__ logK,
                              float* __restrict__ logQ,
                              float* __restrict__ chansum) {
  const int b = blockIdx.z, h = blockIdx.y;
  const int t = threadIdx.x;
  const long n = (long)blockIdx.x * 1024 + t * 4;
  const float* xb = x + ((long)(b * C + h * CPH)) * N + n;
  float4 lk = make_float4(0.f, 0.f, 0.f, 0.f);
  float4 lq = make_float4(0.f, 0.f, 0.f, 0.f);
  __shared__ float wsumS[CPH][4];
  const int lane = t & 63, wid = t >> 6;
#pragma unroll
  for (int c = 0; c < CPH; ++c) {
    const float4 xv = *(const float4*)(xb + (long)c * N);
    const float wk = kw[h * CPH + c], wq = qw[h * CPH + c];
    lk.x += xv.x * wk; lk.y += xv.y * wk; lk.z += xv.z * wk; lk.w += xv.w * wk;
    lq.x += xv.x * wq; lq.y += xv.y * wq; lq.z += xv.z * wq; lq.w += xv.w * wq;
    float s = (xv.x + xv.y) + (xv.z + xv.w);
    s = waveReduceSum(s);
    if (lane == 0) wsumS[c][wid] = s;
  }
  __syncthreads();
  if (t < CPH) {
    const float s = wsumS[t][0] + wsumS[t][1] + wsumS[t][2] + wsumS[t][3];
    atomicAdd(&chansum[b * C + h * CPH + t], s);
  }
  const long lbase = ((long)(b * NH + h)) * N + n;
  *(float4*)(logK + lbase) = lk;
  *(float4*)(logQ + lbase) = lq;
}

// ---------------------------------------------------------------------------
// k2: per-(b,h) softmax stats (max, sum of exp) over N. 256 blocks:
// blockIdx.x = tensorSel*128 + row. Online max/sum, butterfly combine.
__global__ void k2_stats(const float* __restrict__ logK,
                         const float* __restrict__ logQ,
                         float* __restrict__ maxK, float* __restrict__ sumK,
                         float* __restrict__ maxQ, float* __restrict__ sumQ) {
  const int idx = blockIdx.x;
  const int row = idx & 127;
  const bool isQ = idx >= 128;
  const float* src = (isQ ? logQ : logK) + (long)row * N;
  const int t = threadIdx.x;
  float m = -INFINITY, s = 0.f;
  for (int k = 0; k < N / 1024; ++k) {
    const float4 v = *(const float4*)(src + k * 1024 + t * 4);
    const float mv = fmaxf(fmaxf(v.x, v.y), fmaxf(v.z, v.w));
    const float M = fmaxf(m, mv);
    s = s * __expf(m - M) +
        ((__expf(v.x - M) + __expf(v.y - M)) + (__expf(v.z - M) + __expf(v.w - M)));
    m = M;
  }
#pragma unroll
  for (int o = 32; o > 0; o >>= 1) {
    const float mo = __shfl_xor(m, o), so = __shfl_xor(s, o);
    const float M = fmaxf(m, mo);
    s = s * __expf(m - M) + so * __expf(mo - M);
    m = M;
  }
  __shared__ float mS[4], sS[4];
  const int lane = t & 63, wid = t >> 6;
  if (lane == 0) { mS[wid] = m; sS[wid] = s; }
  __syncthreads();
  if (t == 0) {
    float mm = mS[0], ss = sS[0];
    for (int w = 1; w < 4; ++w) {
      const float M = fmaxf(mm, mS[w]);
      ss = ss * __expf(mm - M) + sS[w] * __expf(mS[w] - M);
      mm = M;
    }
    if (isQ) { maxQ[row] = mm; sumQ[row] = ss; }
    else     { maxK[row] = mm; sumK[row] = ss; }
  }
}

// ---------------------------------------------------------------------------
// k3: weighted pooling. res[b,h,c] += sum_n x * exp(logit - max).
// Same tiling as k1. Wave reduce per channel, atomics per block.
__global__ void k3_pool(const float* __restrict__ x,
                        const float* __restrict__ logK,
                        const float* __restrict__ logQ,
                        const float* __restrict__ maxK,
                        const float* __restrict__ maxQ,
                        float* __restrict__ resK, float* __restrict__ resQ) {
  const int b = blockIdx.z, h = blockIdx.y;
  const int t = threadIdx.x;
  const long n = (long)blockIdx.x * 1024 + t * 4;
  const long lbase = ((long)(b * NH + h)) * N + n;
  const float4 lk = *(const float4*)(logK + lbase);
  const float4 lq = *(const float4*)(logQ + lbase);
  const float mk = maxK[b * NH + h], mq = maxQ[b * NH + h];
  const float4 wk = make_float4(__expf(lk.x - mk), __expf(lk.y - mk),
                                __expf(lk.z - mk), __expf(lk.w - mk));
  const float4 wq = make_float4(__expf(lq.x - mq), __expf(lq.y - mq),
                                __expf(lq.z - mq), __expf(lq.w - mq));
  const float* xb = x + ((long)(b * C + h * CPH)) * N + n;
  __shared__ float dkS[CPH][4], dqS[CPH][4];
  const int lane = t & 63, wid = t >> 6;
#pragma unroll
  for (int c = 0; c < CPH; ++c) {
    const float4 xv = *(const float4*)(xb + (long)c * N);
    float dk = (xv.x * wk.x + xv.y * wk.y) + (xv.z * wk.z + xv.w * wk.w);
    float dq = (xv.x * wq.x + xv.y * wq.y) + (xv.z * wq.z + xv.w * wq.w);
#pragma unroll
    for (int o = 32; o > 0; o >>= 1) {
      dk += __shfl_xor(dk, o);
      dq += __shfl_xor(dq, o);
    }
    if (lane == 0) { dkS[c][wid] = dk; dqS[c][wid] = dq; }
  }
  __syncthreads();
  if (t < CPH) {
    atomicAdd(&resK[b * C + h * CPH + t],
              dkS[t][0] + dkS[t][1] + dkS[t][2] + dkS[t][3]);
  } else if (t < 2 * CPH) {
    const int c = t - CPH;
    atomicAdd(&resQ[b * C + h * CPH + c],
              dqS[c][0] + dqS[c][1] + dqS[c][2] + dqS[c][3]);
  }
}

// ---------------------------------------------------------------------------
// k4: finalize. mu, K, Q, grouped MLP gate P, scale/offset, dp. grid(B), 512 thr.
__global__ void k4_final(const float* __restrict__ chansum,
                         const float* __restrict__ resK,
                         const float* __restrict__ resQ,
                         const float* __restrict__ sumK,
                         const float* __restrict__ sumQ,
                         const float* __restrict__ pw1,
                         const float* __restrict__ pb1,
                         const float* __restrict__ pw2,
                         const float* __restrict__ pb2,
                         float* __restrict__ scale,
                         float* __restrict__ offset,
                         float* __restrict__ dpOut) {
  const int b = blockIdx.x;
  const int c = threadIdx.x; // 0..511
  const int h = c >> 4;
  __shared__ float muS[C], h1S[256];
  const float mu = chansum[b * C + c] * (1.f / N);
  const float Kv = resK[b * C + c] / sumK[b * NH + h] - mu;
  const float Qv = resQ[b * C + c] / sumQ[b * NH + h] - mu;
  muS[c] = mu;
  __syncthreads();
  if (c < 256) {
    const int g = c >> 3; // group of 8 outputs, 16 inputs each
    float a = pb1[c];
#pragma unroll
    for (int i = 0; i < 16; ++i) a += muS[g * 16 + i] * pw1[c * 16 + i];
    h1S[c] = fmaxf(a, 0.f);
  }
  __syncthreads();
  float a = pb2[c];
  const int g2 = c >> 4;
#pragma unroll
  for (int i = 0; i < 8; ++i) a += h1S[g2 * 8 + i] * pw2[c * 8 + i];
  const float P = 1.f / (1.f + __expf(-a));
  scale[b * C + c] = P;
  offset[b * C + c] = (Kv - Qv) * P;
  // dp[b] = mean_c(K*Q)
  float p = waveReduceSum(Kv * Qv);
  __shared__ float pS[8];
  const int lane = c & 63, wid = c >> 6;
  if (lane == 0) pS[wid] = p;
  __syncthreads();
  if (c == 0) {
    float tot = 0.f;
    for (int w = 0; w < 8; ++w) tot += pS[w];
    dpOut[b] = tot * (1.f / C);
  }
}

// ---------------------------------------------------------------------------
// k5: y = x * scale[b,c] + offset[b,c]. grid (N/4096, C, B), block 256.
__global__ void k5_out(const float* __restrict__ x,
                       const float* __restrict__ scale,
                       const float* __restrict__ offset,
                       float* __restrict__ y) {
  const int b = blockIdx.z, c = blockIdx.y;
  const int t = threadIdx.x;
  const long base = ((long)(b * C + c)) * N + (long)blockIdx.x * 4096;
  const float s = scale[b * C + c], o = offset[b * C + c];
#pragma unroll
  for (int k = 0; k < 4; ++k) {
    const long i = base + (long)(k * 256 + t) * 4;
    float4 v = *(const float4*)(x + i);
    v.x = v.x * s + o; v.y = v.y * s + o;
    v.z = v.z * s + o; v.w = v.w * s + o;
    *(float4*)(y + i) = v;
  }
}

} // namespace

extern "C" void kernel_launch(void* const* d_in, const int* in_sizes, int n_in,
                              void* d_out, int out_size, void* d_ws, size_t ws_size,
                              hipStream_t stream) {
  const float* x   = (const float*)d_in[0];
  const float* pw1 = (const float*)d_in[1];
  const float* pb1 = (const float*)d_in[2];
  const float* pw2 = (const float*)d_in[3];
  const float* pb2 = (const float*)d_in[4];
  const float* kw  = (const float*)d_in[5];
  // d_in[6] = kb, d_in[8] = qb: biases cancel in softmax, unused.
  const float* qw  = (const float*)d_in[7];
  float* out = (float*)d_out;
  float* ws  = (float*)d_ws;

  // small workspace layout (floats)
  float* chansum = ws;          // 2048 (accumulated -> must zero)
  float* resK    = ws + 2048;   // 2048 (accumulated -> must zero)
  float* resQ    = ws + 4096;   // 2048 (accumulated -> must zero)
  float* maxK    = ws + 6144;   // 128
  float* sumK    = ws + 6272;   // 128
  float* maxQ    = ws + 6400;   // 128
  float* sumQ    = ws + 6528;   // 128
  float* scale   = ws + 6656;   // 2048
  float* offset  = ws + 8704;   // 2048
  const long smallFloats = 10752;

  // logits scratch: prefer d_ws; else stage in d_out (consumed before k5 rewrites)
  float *logK, *logQ;
  if (ws_size >= (size_t)(smallFloats + 2 * BHN) * sizeof(float)) {
    logK = ws + smallFloats;
    logQ = logK + BHN;
  } else {
    logK = out;
    logQ = out + BHN;
  }

  hipMemsetAsync(ws, 0, 6144 * sizeof(float), stream);

  const dim3 gtile(N / 1024, NH, B);
  hipLaunchKernelGGL(k1_logits_sum, gtile, dim3(256), 0, stream,
                     x, kw, qw, logK, logQ, chansum);
  hipLaunchKernelGGL(k2_stats, dim3(256), dim3(256), 0, stream,
                     logK, logQ, maxK, sumK, maxQ, sumQ);
  hipLaunchKernelGGL(k3_pool, gtile, dim3(256), 0, stream,
                     x, logK, logQ, maxK, maxQ, resK, resQ);
  hipLaunchKernelGGL(k4_final, dim3(B), dim3(C), 0, stream,
                     chansum, resK, resQ, sumK, sumQ,
                     pw1, pb1, pw2, pb2, scale, offset, out + YSIZE);
  hipLaunchKernelGGL(k5_out, dim3(N / 4096, C, B), dim3(256), 0, stream,
                     x, scale, offset, out);
}

// Round 2
// 171.741 us; speedup vs baseline: 1.3486x; 1.3486x over previous
//
#include <hip/hip_runtime.h>
#include <math.h>

namespace {

constexpr int B = 4;
constexpr int C = 512;
constexpr int NH = 32;          // heads
constexpr int CPH = 16;         // channels per head
constexpr int N = 32 * 32 * 32; // 32768 spatial
constexpr int NCHUNK = 32;      // chunks of 1024 n per (b,h)
constexpr long YSIZE = (long)B * C * N;  // 67,108,864

__device__ inline float wrs(float v) {
#pragma unroll
  for (int o = 32; o > 0; o >>= 1) v += __shfl_xor(v, o);
  return v;
}
__device__ inline float wrm(float v) {
#pragma unroll
  for (int o = 32; o > 0; o >>= 1) v = fmaxf(v, __shfl_xor(v, o));
  return v;
}

// ---------------------------------------------------------------------------
// kA: single pass over x. Per (b,h,chunk) block of 1024 n:
//  - K/Q raw logits (bias and -mu*w cancel in softmax)
//  - block-local max m, sumexp s, per-channel weighted sums d[c] = sum x*exp(l-m)
//  - per-channel plain sums (for mu)
// Writes 52 floats per block. grid (32, NH, B), block 256.
__global__ __launch_bounds__(256) void kA(const float* __restrict__ x,
                                          const float* __restrict__ kw,
                                          const float* __restrict__ qw,
                                          float* __restrict__ pmK,
                                          float* __restrict__ psK,
                                          float* __restrict__ pmQ,
                                          float* __restrict__ psQ,
                                          float* __restrict__ pdK,
                                          float* __restrict__ pdQ,
                                          float* __restrict__ pcs) {
  const int b = blockIdx.z, h = blockIdx.y, j = blockIdx.x;
  const int t = threadIdx.x, lane = t & 63, wid = t >> 6;
  const long n = (long)j * 1024 + t * 4;
  const float* xb = x + ((long)(b * C + h * CPH)) * N + n;

  float4 xv[CPH];
  float4 lk = make_float4(0.f, 0.f, 0.f, 0.f);
  float4 lq = make_float4(0.f, 0.f, 0.f, 0.f);
#pragma unroll
  for (int c = 0; c < CPH; ++c) {
    xv[c] = *(const float4*)(xb + (long)c * N);
    const float wk = kw[h * CPH + c], wq = qw[h * CPH + c];
    lk.x += xv[c].x * wk; lk.y += xv[c].y * wk;
    lk.z += xv[c].z * wk; lk.w += xv[c].w * wk;
    lq.x += xv[c].x * wq; lq.y += xv[c].y * wq;
    lq.z += xv[c].z * wq; lq.w += xv[c].w * wq;
  }
  // block max (K and Q)
  float mk = wrm(fmaxf(fmaxf(lk.x, lk.y), fmaxf(lk.z, lk.w)));
  float mq = wrm(fmaxf(fmaxf(lq.x, lq.y), fmaxf(lq.z, lq.w)));
  __shared__ float mS[8];
  if (lane == 0) { mS[wid] = mk; mS[4 + wid] = mq; }
  __syncthreads();
  mk = fmaxf(fmaxf(mS[0], mS[1]), fmaxf(mS[2], mS[3]));
  mq = fmaxf(fmaxf(mS[4], mS[5]), fmaxf(mS[6], mS[7]));

  const float4 ek = make_float4(__expf(lk.x - mk), __expf(lk.y - mk),
                                __expf(lk.z - mk), __expf(lk.w - mk));
  const float4 eq = make_float4(__expf(lq.x - mq), __expf(lq.y - mq),
                                __expf(lq.z - mq), __expf(lq.w - mq));
  float sk = wrs((ek.x + ek.y) + (ek.z + ek.w));
  float sq = wrs((eq.x + eq.y) + (eq.z + eq.w));
  __shared__ float sS[8];
  if (lane == 0) { sS[wid] = sk; sS[4 + wid] = sq; }

  __shared__ float dS[3][CPH][4];
#pragma unroll
  for (int c = 0; c < CPH; ++c) {
    float dk = (xv[c].x * ek.x + xv[c].y * ek.y) + (xv[c].z * ek.z + xv[c].w * ek.w);
    float dq = (xv[c].x * eq.x + xv[c].y * eq.y) + (xv[c].z * eq.z + xv[c].w * eq.w);
    float cs = (xv[c].x + xv[c].y) + (xv[c].z + xv[c].w);
    dk = wrs(dk); dq = wrs(dq); cs = wrs(cs);
    if (lane == 0) { dS[0][c][wid] = dk; dS[1][c][wid] = dq; dS[2][c][wid] = cs; }
  }
  __syncthreads();
  const long pj = (long)(b * NH + h) * NCHUNK + j;
  if (t == 0) {
    pmK[pj] = mk; pmQ[pj] = mq;
    psK[pj] = (sS[0] + sS[1]) + (sS[2] + sS[3]);
    psQ[pj] = (sS[4] + sS[5]) + (sS[6] + sS[7]);
  }
  if (t < CPH) {
    pdK[pj * CPH + t] = (dS[0][t][0] + dS[0][t][1]) + (dS[0][t][2] + dS[0][t][3]);
  } else if (t < 2 * CPH) {
    const int c = t - CPH;
    pdQ[pj * CPH + c] = (dS[1][c][0] + dS[1][c][1]) + (dS[1][c][2] + dS[1][c][3]);
  } else if (t < 3 * CPH) {
    const int c = t - 2 * CPH;
    pcs[pj * CPH + c] = (dS[2][c][0] + dS[2][c][1]) + (dS[2][c][2] + dS[2][c][3]);
  }
}

// ---------------------------------------------------------------------------
// k4: combine partials + finalize. grid(B), 512 threads (thread = channel).
__global__ __launch_bounds__(512) void k4(const float* __restrict__ pmK,
                                          const float* __restrict__ psK,
                                          const float* __restrict__ pmQ,
                                          const float* __restrict__ psQ,
                                          const float* __restrict__ pdK,
                                          const float* __restrict__ pdQ,
                                          const float* __restrict__ pcs,
                                          const float* __restrict__ pw1,
                                          const float* __restrict__ pb1,
                                          const float* __restrict__ pw2,
                                          const float* __restrict__ pb2,
                                          float* __restrict__ scale,
                                          float* __restrict__ offset,
                                          float* __restrict__ dpOut) {
  const int b = blockIdx.x;
  const int c = threadIdx.x;           // 0..511
  const int h = c >> 4, i = c & 15;
  const long base = (long)(b * NH + h) * NCHUNK;

  float MK = -INFINITY, MQ = -INFINITY;
  for (int j = 0; j < NCHUNK; ++j) {
    MK = fmaxf(MK, pmK[base + j]);
    MQ = fmaxf(MQ, pmQ[base + j]);
  }
  float sk = 0.f, sq = 0.f, dk = 0.f, dq = 0.f, cs = 0.f;
  for (int j = 0; j < NCHUNK; ++j) {
    const float ekj = __expf(pmK[base + j] - MK);
    const float eqj = __expf(pmQ[base + j] - MQ);
    sk += psK[base + j] * ekj;
    sq += psQ[base + j] * eqj;
    dk += pdK[(base + j) * CPH + i] * ekj;
    dq += pdQ[(base + j) * CPH + i] * eqj;
    cs += pcs[(base + j) * CPH + i];
  }
  const float mu = cs * (1.f / N);
  const float Kv = dk / sk - mu;
  const float Qv = dq / sq - mu;

  __shared__ float muS[C], h1S[256];
  muS[c] = mu;
  __syncthreads();
  if (c < 256) {
    const int g = c >> 3;
    float a = pb1[c];
#pragma unroll
    for (int k = 0; k < 16; ++k) a += muS[g * 16 + k] * pw1[c * 16 + k];
    h1S[c] = fmaxf(a, 0.f);
  }
  __syncthreads();
  float a = pb2[c];
  const int g2 = c >> 4;
#pragma unroll
  for (int k = 0; k < 8; ++k) a += h1S[g2 * 8 + k] * pw2[c * 8 + k];
  const float P = 1.f / (1.f + __expf(-a));
  scale[b * C + c] = P;
  offset[b * C + c] = (Kv - Qv) * P;

  float p = wrs(Kv * Qv);
  __shared__ float pS[8];
  const int lane = c & 63, wid = c >> 6;
  if (lane == 0) pS[wid] = p;
  __syncthreads();
  if (c == 0) {
    float tot = 0.f;
    for (int w = 0; w < 8; ++w) tot += pS[w];
    dpOut[b] = tot * (1.f / C);
  }
}

// ---------------------------------------------------------------------------
// k5: y = x * scale[b,c] + offset[b,c]. grid (N/4096, C, B), block 256.
__global__ __launch_bounds__(256) void k5(const float* __restrict__ x,
                                          const float* __restrict__ scale,
                                          const float* __restrict__ offset,
                                          float* __restrict__ y) {
  const int b = blockIdx.z, cc = blockIdx.y;
  const int t = threadIdx.x;
  const long base = ((long)(b * C + cc)) * N + (long)blockIdx.x * 4096;
  const float s = scale[b * C + cc], o = offset[b * C + cc];
#pragma unroll
  for (int k = 0; k < 4; ++k) {
    const long i = base + (long)(k * 256 + t) * 4;
    float4 v = *(const float4*)(x + i);
    v.x = v.x * s + o; v.y = v.y * s + o;
    v.z = v.z * s + o; v.w = v.w * s + o;
    *(float4*)(y + i) = v;
  }
}

} // namespace

extern "C" void kernel_launch(void* const* d_in, const int* in_sizes, int n_in,
                              void* d_out, int out_size, void* d_ws, size_t ws_size,
                              hipStream_t stream) {
  const float* x   = (const float*)d_in[0];
  const float* pw1 = (const float*)d_in[1];
  const float* pb1 = (const float*)d_in[2];
  const float* pw2 = (const float*)d_in[3];
  const float* pb2 = (const float*)d_in[4];
  const float* kw  = (const float*)d_in[5];
  // d_in[6]=kb, d_in[8]=qb unused: biases cancel in softmax (shift-invariant),
  // and sum_n attn = 1 folds mean-subtraction into the finalize step.
  const float* qw  = (const float*)d_in[7];
  float* out = (float*)d_out;
  float* ws  = (float*)d_ws;

  // scale/offset always in ws (read by k5 while k5 writes out)
  float* scale  = ws;          // 2048
  float* offset = ws + 2048;   // 2048

  // partials: 4*4096 + 3*65536 = 212992 floats (~852 KB)
  constexpr long PM = (long)B * NH * NCHUNK;   // 4096
  constexpr long PD = PM * CPH;                // 65536
  constexpr long partialFloats = 4 * PM + 3 * PD;
  float* pbase;
  if (ws_size >= (size_t)(4096 + partialFloats) * sizeof(float)) {
    pbase = ws + 4096;
  } else {
    pbase = out;  // consumed by k4 before k5 overwrites out
  }
  float* pmK = pbase;
  float* psK = pbase + PM;
  float* pmQ = pbase + 2 * PM;
  float* psQ = pbase + 3 * PM;
  float* pdK = pbase + 4 * PM;
  float* pdQ = pbase + 4 * PM + PD;
  float* pcs = pbase + 4 * PM + 2 * PD;

  hipLaunchKernelGGL(kA, dim3(NCHUNK, NH, B), dim3(256), 0, stream,
                     x, kw, qw, pmK, psK, pmQ, psQ, pdK, pdQ, pcs);
  hipLaunchKernelGGL(k4, dim3(B), dim3(C), 0, stream,
                     pmK, psK, pmQ, psQ, pdK, pdQ, pcs,
                     pw1, pb1, pw2, pb2, scale, offset, out + YSIZE);
  hipLaunchKernelGGL(k5, dim3(N / 4096, C, B), dim3(256), 0, stream,
                     x, scale, offset, out);
}